// Round 7
// baseline (251.655 us; speedup 1.0000x reference)
//
#include <hip/hip_runtime.h>
#include <hip/hip_bf16.h>

// Problem constants
#define NROWS 65536      // 64*32*32
#define DIM   256
#define NCODE 1024
#define OUT_ELEMS 16777216  // NROWS*DIM

typedef __attribute__((ext_vector_type(8))) short bf16x8;
typedef __attribute__((ext_vector_type(4))) float f32x4;

__device__ __forceinline__ unsigned umin_(unsigned a, unsigned b) { return a < b ? a : b; }

// RNE float->bf16 (finite inputs) — must stay bit-identical across rounds
__device__ __forceinline__ unsigned short f2bf(float f) {
    unsigned b = __builtin_bit_cast(unsigned, f);
    return (unsigned short)((b + 0x7FFFu + ((b >> 16) & 1u)) >> 16);
}

// ---------------------------------------------------------------------------
// K_prep: blocks 0..127: codebook fp32 -> bf16 in MFMA B-fragment order.
//   eb[((t*8+ks)*64 + lane)*8 + j] = e[n][k], n=t*16+(lane&15), k=ks*32+(lane>>4)*8+j
// blocks 128..131: per-code squared norms + 0.25 key offset (fp32 exact).
// block 132: zero counts/sumsq (folded memset — free, keep from R6).
// ---------------------------------------------------------------------------
__global__ __launch_bounds__(256)
void k_prep(const float* __restrict__ e, float* __restrict__ seb,
            unsigned short* __restrict__ eb, int* __restrict__ counts,
            double* __restrict__ sumsq) {
    int b = blockIdx.x;
    if (b < 128) {
        int g = b * 256 + threadIdx.x;   // 0 .. 32767
        int lane = g & 63;
        int ks   = (g >> 6) & 7;
        int t    = g >> 9;
        int n  = t * 16 + (lane & 15);
        int k0 = ks * 32 + (lane >> 4) * 8;
        const float* src = e + (size_t)n * DIM + k0;
        bf16x8 o;
        #pragma unroll
        for (int j = 0; j < 8; ++j) o[j] = (short)f2bf(src[j]);
        *(bf16x8*)(eb + (size_t)g * 8) = o;
    } else if (b < 132) {
        int c = (b - 128) * 256 + threadIdx.x;
        const float4* r = (const float4*)(e + (size_t)c * DIM);
        float s = 0.f;
        #pragma unroll
        for (int i = 0; i < DIM / 4; ++i) {
            float4 v = r[i];
            s += v.x * v.x + v.y * v.y + v.z * v.z + v.w * v.w;
        }
        seb[c] = s + 0.25f;
    } else {
        #pragma unroll
        for (int j = 0; j < 4; ++j) counts[threadIdx.x * 4 + j] = 0;
        if (threadIdx.x == 0) *sumsq = 0.0;
    }
}

// ---------------------------------------------------------------------------
// K_main (R7): CODE-SPLIT register-streamed argmin + fused epilogue.
// R6 post-mortem: dispatch-count residual is FIXED (~84 us) -> only kernel
// time is winnable; last-block tail reverted.  Cross-round evidence: per-tile
// time is ~2400-2900 cyc in EVERY structure (latency tax, ~90% stall) ->
// attack with MORE waves/SIMD:
//   - 1024 blocks x 256 thr, __launch_bounds__(256,4): 4 blocks/CU =
//     16 waves/CU = 4/SIMD (2x R4).  VGPR ~100 <= 128 so legal.
//   - Wave pair (2w,2w+1) handles the SAME 32 rows, DISJOINT 512-code
//     halves (32 tiles each; wave streams 256 KB of eb).  Min-combine via
//     one 512 B LDS exchange + 1 barrier; then wave half owns stripe
//     s=half: counts atomics + K2 epilogue for its 16 rows (exact fp32).
// Same total MFMA; bit-identical per-code arithmetic; L2 eb traffic 1 GB.
// ALIASING: eb at d_out+32MB == out rows [32768,33280) == blocks 512..519:
// they SKIP out-stores, record codes in fixidx; k_fix patches after.
// MFMA layouts (proven): A[m=lane&15][k=(lane>>4)*8+j], B[n=lane&15][k=same],
// D col(code)=lane&15, row=(lane>>4)*4+reg.
// argmin key: (bits(se+0.25-2dot) & ~1023) | code -> min_u32. Hist fused.
// ---------------------------------------------------------------------------
__global__ __launch_bounds__(256, 4)
void k_main(const float* __restrict__ x,
            const float* __restrict__ e,
            const unsigned short* __restrict__ eb,
            const float* __restrict__ seb,
            float* __restrict__ out,
            int* __restrict__ counts,
            double* __restrict__ sumsq,
            int* __restrict__ fixidx) {
    const int tid  = threadIdx.x;
    const int wid  = tid >> 6;
    const int half = wid & 1;        // codebook half this wave scans
    const int rg   = wid >> 1;       // row-group within block
    const int l  = tid & 63;
    const int lr = l & 15;
    const int lh = l >> 4;
    const int row0 = blockIdx.x * 64 + rg * 32;
    const int T0   = half * 32;      // first tile of this wave's half
    const int code0 = half * 512;

    const bf16x8* __restrict__ ebv = (const bf16x8*)eb;  // fragment units

    // B preload: tiles T0, T0+1 into register double-buffer (issue FIRST)
    bf16x8 bA[8], bB[8];
    #pragma unroll
    for (int ks = 0; ks < 8; ++ks) {
        bA[ks] = ebv[(size_t)T0 * 512 + ks * 64 + l];
        bB[ks] = ebv[(size_t)(T0 + 1) * 512 + ks * 64 + l];
    }

    // A fragments: 2 stripes x 8 ksteps, fp32 loads + in-reg cvt
    // (pair-partner wave reads the same rows: second read is same-CU L2 hit)
    bf16x8 af[2][8];
    #pragma unroll
    for (int s = 0; s < 2; ++s) {
        const float* rp = x + (size_t)(row0 + s * 16 + lr) * DIM + lh * 8;
        #pragma unroll
        for (int ks = 0; ks < 8; ++ks) {
            float4 a = *(const float4*)(rp + ks * 32);
            float4 bq = *(const float4*)(rp + ks * 32 + 4);
            bf16x8 o;
            o[0] = (short)f2bf(a.x);  o[1] = (short)f2bf(a.y);
            o[2] = (short)f2bf(a.z);  o[3] = (short)f2bf(a.w);
            o[4] = (short)f2bf(bq.x); o[5] = (short)f2bf(bq.y);
            o[6] = (short)f2bf(bq.z); o[7] = (short)f2bf(bq.w);
            af[s][ks] = o;
        }
    }

    unsigned best[2][4];
    #pragma unroll
    for (int s = 0; s < 2; ++s)
        #pragma unroll
        for (int r = 0; r < 4; ++r) best[s][r] = 0xFFFFFFFFu;

#define PHASE(TI, B, RT) do {                                                \
        const int ti_ = (TI);                                                \
        const int rt_ = (RT);                                                \
        float sv_ = seb[code0 + ti_ * 16 + lr];                              \
        f32x4 a0_ = (f32x4){0.f, 0.f, 0.f, 0.f};                             \
        f32x4 a1_ = (f32x4){0.f, 0.f, 0.f, 0.f};                             \
        _Pragma("unroll")                                                    \
        for (int ks = 0; ks < 8; ++ks) {                                     \
            a0_ = __builtin_amdgcn_mfma_f32_16x16x32_bf16(af[0][ks], B[ks], a0_, 0, 0, 0); \
            a1_ = __builtin_amdgcn_mfma_f32_16x16x32_bf16(af[1][ks], B[ks], a1_, 0, 0, 0); \
            if (rt_ >= 0) B[ks] = ebv[(size_t)rt_ * 512 + ks * 64 + l];      \
        }                                                                    \
        unsigned nl_ = (unsigned)(code0 + ti_ * 16) | (unsigned)lr;          \
        _Pragma("unroll")                                                    \
        for (int r = 0; r < 4; ++r) {                                        \
            float s0_ = fmaf(-2.0f, a0_[r], sv_);                            \
            best[0][r] = umin_(best[0][r],                                   \
                (__builtin_bit_cast(unsigned, s0_) & 0xFFFFFC00u) | nl_);    \
            float s1_ = fmaf(-2.0f, a1_[r], sv_);                            \
            best[1][r] = umin_(best[1][r],                                   \
                (__builtin_bit_cast(unsigned, s1_) & 0xFFFFFC00u) | nl_);    \
        }                                                                    \
    } while (0)

    #pragma unroll 1
    for (int ti = 0; ti < 30; ti += 2) {
        PHASE(ti,     bA, T0 + ti + 2);
        PHASE(ti + 1, bB, T0 + ti + 3);
    }
    PHASE(30, bA, -1);
    PHASE(31, bB, -1);
#undef PHASE

    // reduce over the 16 code-lanes (same lh): xor 1,2,4,8
    #pragma unroll
    for (int s = 0; s < 2; ++s)
        #pragma unroll
        for (int r = 0; r < 4; ++r) {
            unsigned v = best[s][r];
            #pragma unroll
            for (int m = 1; m <= 8; m <<= 1)
                v = umin_(v, (unsigned)__shfl_xor((int)v, m, 64));
            best[s][r] = v;
        }

    // ---- cross-half min-combine (wave pair shares the same 32 rows) ----
    __shared__ unsigned cmb[2][2][2][4][4];   // [rg][half][s][r][lh], 512 B
    if (lr == 0) {
        #pragma unroll
        for (int s = 0; s < 2; ++s)
            #pragma unroll
            for (int r = 0; r < 4; ++r)
                cmb[rg][half][s][r][lh] = best[s][r];
    }
    __syncthreads();
    #pragma unroll
    for (int s = 0; s < 2; ++s)
        #pragma unroll
        for (int r = 0; r < 4; ++r)
            best[s][r] = umin_(best[s][r], cmb[rg][half ^ 1][s][r][lh]);

    // eb-overlap blocks: rows [32768,33280) == out bytes [32MB,32.5MB)
    const bool skipout = (blockIdx.x >= 512 && blockIdx.x < 520);

    // duty split: wave `half` owns stripe s = half (16 rows)
    const int so = half;
    if (lr == 0) {
        #pragma unroll
        for (int r = 0; r < 4; ++r) {
            int code = (int)(best[so][r] & 1023u);
            atomicAdd(&counts[code], 1);
            if (skipout)
                fixidx[row0 + so * 16 + lh * 4 + r - 32768] = code;
        }
    }

    // fused K2 epilogue: 16 rows (own stripe), 2 groups of 8 (K2's exact math)
    float local = 0.f;
    #pragma unroll
    for (int g = 0; g < 2; ++g) {
        int code[8];
        #pragma unroll
        for (int j = 0; j < 8; ++j) {
            const int off = g * 8 + j;           // 0..15 within stripe
            const int h = off >> 2, r = off & 3; // row = so*16 + h*4 + r
            code[j] = (int)((unsigned)__shfl((int)best[so][r], h << 4, 64) & 1023u);
        }
        float4 xv[8];
        #pragma unroll
        for (int j = 0; j < 8; ++j)
            xv[j] = ((const float4*)x)[(size_t)(row0 + so * 16 + g * 8 + j) * 64 + l];
        float4 qv[8];
        #pragma unroll
        for (int j = 0; j < 8; ++j)
            qv[j] = ((const float4*)e)[(size_t)code[j] * 64 + l];
        #pragma unroll
        for (int j = 0; j < 8; ++j) {
            float4 d, o;
            d.x = qv[j].x - xv[j].x; d.y = qv[j].y - xv[j].y;
            d.z = qv[j].z - xv[j].z; d.w = qv[j].w - xv[j].w;
            o.x = xv[j].x + d.x;  o.y = xv[j].y + d.y;
            o.z = xv[j].z + d.z;  o.w = xv[j].w + d.w;
            if (!skipout)
                ((float4*)out)[(size_t)(row0 + so * 16 + g * 8 + j) * 64 + l] = o;
            local += d.x * d.x + d.y * d.y + d.z * d.z + d.w * d.w;
        }
    }
    #pragma unroll
    for (int m = 32; m >= 1; m >>= 1) local += __shfl_xor(local, m, 64);
    __shared__ float red[4];
    if (l == 0) red[wid] = local;
    __syncthreads();
    if (tid == 0) {
        float s = red[0] + red[1] + red[2] + red[3];
        atomicAdd(sumsq, (double)s);
    }
}

// ---------------------------------------------------------------------------
// K_fix: rewrite out rows [32768, 33280) (deferred because they alias eb).
// Runs after k_main (stream-ordered; eb dead).  Same arithmetic as epilogue.
// ---------------------------------------------------------------------------
__global__ __launch_bounds__(256)
void k_fix(const float* __restrict__ x, const float* __restrict__ e,
           const int* __restrict__ fixidx, float* __restrict__ out) {
    const int w = threadIdx.x >> 6;
    const int l = threadIdx.x & 63;
    const int rbase = blockIdx.x * 32 + w * 8;   // 0..511 local
    int k[8];
    #pragma unroll
    for (int r = 0; r < 8; ++r) k[r] = fixidx[rbase + r];
    float4 xv[8];
    #pragma unroll
    for (int r = 0; r < 8; ++r)
        xv[r] = ((const float4*)x)[(size_t)(32768 + rbase + r) * 64 + l];
    float4 qv[8];
    #pragma unroll
    for (int r = 0; r < 8; ++r)
        qv[r] = ((const float4*)e)[(size_t)k[r] * 64 + l];
    #pragma unroll
    for (int r = 0; r < 8; ++r) {
        float4 d, o;
        d.x = qv[r].x - xv[r].x; d.y = qv[r].y - xv[r].y;
        d.z = qv[r].z - xv[r].z; d.w = qv[r].w - xv[r].w;
        o.x = xv[r].x + d.x;  o.y = xv[r].y + d.y;
        o.z = xv[r].z + d.z;  o.w = xv[r].w + d.w;
        ((float4*)out)[(size_t)(32768 + rbase + r) * 64 + l] = o;
    }
}

// ---------------------------------------------------------------------------
// K4: finalize loss + perplexity (single block)
// ---------------------------------------------------------------------------
__global__ __launch_bounds__(256)
void k_fin(const int* __restrict__ counts, const double* __restrict__ sumsq,
           float* __restrict__ out_scalars) {
    float local = 0.f;
    for (int c = threadIdx.x; c < NCODE; c += 256) {
        float p = (float)counts[c] * (1.0f / 65536.0f);
        local += p * logf(p + 1e-10f);
    }
    #pragma unroll
    for (int m = 32; m >= 1; m >>= 1) local += __shfl_xor(local, m, 64);
    __shared__ float red[4];
    if ((threadIdx.x & 63) == 0) red[threadIdx.x >> 6] = local;
    __syncthreads();
    if (threadIdx.x == 0) {
        float s = red[0] + red[1] + red[2] + red[3];
        float perp = expf(-s);
        float m = (float)(*sumsq * (1.0 / 16777216.0));
        float loss = m + 0.25f * m;
        out_scalars[0] = loss;
        out_scalars[1] = perp;
    }
}

// ---------------------------------------------------------------------------
extern "C" void kernel_launch(void* const* d_in, const int* in_sizes, int n_in,
                              void* d_out, int out_size, void* d_ws, size_t ws_size,
                              hipStream_t stream) {
    const float* x   = (const float*)d_in[0];   // [65536, 256]
    const float* emb = (const float*)d_in[1];   // [1024, 256]
    float* out = (float*)d_out;                 // [16777216 + 2]

    // small workspace (~11 KB)
    float*    seb    = (float*)d_ws;                        // 4 KB
    int*      counts = (int*)((char*)d_ws + 4096);          // 4 KB
    double*   sumsq  = (double*)((char*)d_ws + 8192);       // 8 B
    int*      fixidx = (int*)((char*)d_ws + 8704);          // 2 KB (512 rows)

    // eb scratch lives in d_out at +32MB: read by k_main, whose out-writes
    // SKIP that byte range (blocks 512..519); k_fix patches it afterwards.
    unsigned short* eb = (unsigned short*)((char*)d_out + 33554432); // 512 KB

    k_prep <<<133,        256, 0, stream>>>(emb, seb, eb, counts, sumsq);
    k_main <<<NROWS / 64, 256, 0, stream>>>(x, emb, eb, seb, out, counts, sumsq, fixidx);
    k_fix  <<<16,         256, 0, stream>>>(x, emb, fixidx, out);
    k_fin  <<<1,          256, 0, stream>>>(counts, sumsq, out + OUT_ELEMS);
}

// Round 8
// 181.006 us; speedup vs baseline: 1.3903x; 1.3903x over previous
//
#include <hip/hip_runtime.h>
#include <hip/hip_bf16.h>

// Problem constants
#define NROWS 65536      // 64*32*32
#define DIM   256
#define NCODE 1024
#define OUT_ELEMS 16777216  // NROWS*DIM

typedef __attribute__((ext_vector_type(8))) short bf16x8;
typedef __attribute__((ext_vector_type(4))) float f32x4;

__device__ __forceinline__ unsigned umin_(unsigned a, unsigned b) { return a < b ? a : b; }

// RNE float->bf16 (finite inputs) — must stay bit-identical across rounds
__device__ __forceinline__ unsigned short f2bf(float f) {
    unsigned b = __builtin_bit_cast(unsigned, f);
    return (unsigned short)((b + 0x7FFFu + ((b >> 16) & 1u)) >> 16);
}

// ---------------------------------------------------------------------------
// K_prep: blocks 0..127: codebook fp32 -> bf16 in MFMA B-fragment order.
//   eb[((t*8+ks)*64 + lane)*8 + j] = e[n][k], n=t*16+(lane&15), k=ks*32+(lane>>4)*8+j
// blocks 128..131: per-code squared norms + 0.25 key offset (fp32 exact).
// block 132: zero counts/sumsq (folded memset).
// ---------------------------------------------------------------------------
__global__ __launch_bounds__(256)
void k_prep(const float* __restrict__ e, float* __restrict__ seb,
            unsigned short* __restrict__ eb, int* __restrict__ counts,
            double* __restrict__ sumsq) {
    int b = blockIdx.x;
    if (b < 128) {
        int g = b * 256 + threadIdx.x;   // 0 .. 32767
        int lane = g & 63;
        int ks   = (g >> 6) & 7;
        int t    = g >> 9;
        int n  = t * 16 + (lane & 15);
        int k0 = ks * 32 + (lane >> 4) * 8;
        const float* src = e + (size_t)n * DIM + k0;
        bf16x8 o;
        #pragma unroll
        for (int j = 0; j < 8; ++j) o[j] = (short)f2bf(src[j]);
        *(bf16x8*)(eb + (size_t)g * 8) = o;
    } else if (b < 132) {
        int c = (b - 128) * 256 + threadIdx.x;
        const float4* r = (const float4*)(e + (size_t)c * DIM);
        float s = 0.f;
        #pragma unroll
        for (int i = 0; i < DIM / 4; ++i) {
            float4 v = r[i];
            s += v.x * v.x + v.y * v.y + v.z * v.z + v.w * v.w;
        }
        seb[c] = s + 0.25f;
    } else {
        #pragma unroll
        for (int j = 0; j < 4; ++j) counts[threadIdx.x * 4 + j] = 0;
        if (threadIdx.x == 0) *sumsq = 0.0;
    }
}

// ---------------------------------------------------------------------------
// K_main (R8): CODE-SPLIT register-streamed argmin + fused epilogue.
// R7 post-mortem: __launch_bounds__(256,4) squeezed the allocator to 64
// VGPR -> massive scratch spills (FETCH/WRITE doubled, MfmaUtil 9%).  The
// code-split TLP theory was never tested.  Fix = ONE variable: revert to
// __launch_bounds__(256,2) (R4's proven allocator config, ~100 VGPR,
// spill-free).  Per m69's measured tiers, VGPR<=128 still admits 16
// waves/CU, so the 1024-block grid gives 4 blocks/CU resident naturally.
//   - Wave pair (2w,2w+1): SAME 32 rows, DISJOINT 512-code halves
//     (32 tiles each); min-combine via 512 B LDS exchange + 1 barrier;
//     wave `half` then owns stripe s=half (counts + epilogue for 16 rows).
// Same total MFMA; bit-identical per-code arithmetic; 1 GB L2 B-traffic.
// ALIASING: eb at d_out+32MB == out rows [32768,33280) == blocks 512..519:
// they SKIP out-stores, record codes in fixidx; k_fix patches after.
// MFMA layouts (proven): A[m=lane&15][k=(lane>>4)*8+j], B[n=lane&15][k=same],
// D col(code)=lane&15, row=(lane>>4)*4+reg.
// argmin key: (bits(se+0.25-2dot) & ~1023) | code -> min_u32. Hist fused.
// ---------------------------------------------------------------------------
__global__ __launch_bounds__(256, 2)
void k_main(const float* __restrict__ x,
            const float* __restrict__ e,
            const unsigned short* __restrict__ eb,
            const float* __restrict__ seb,
            float* __restrict__ out,
            int* __restrict__ counts,
            double* __restrict__ sumsq,
            int* __restrict__ fixidx) {
    const int tid  = threadIdx.x;
    const int wid  = tid >> 6;
    const int half = wid & 1;        // codebook half this wave scans
    const int rg   = wid >> 1;       // row-group within block
    const int l  = tid & 63;
    const int lr = l & 15;
    const int lh = l >> 4;
    const int row0 = blockIdx.x * 64 + rg * 32;
    const int T0   = half * 32;      // first tile of this wave's half
    const int code0 = half * 512;

    const bf16x8* __restrict__ ebv = (const bf16x8*)eb;  // fragment units

    // B preload: tiles T0, T0+1 into register double-buffer (issue FIRST)
    bf16x8 bA[8], bB[8];
    #pragma unroll
    for (int ks = 0; ks < 8; ++ks) {
        bA[ks] = ebv[(size_t)T0 * 512 + ks * 64 + l];
        bB[ks] = ebv[(size_t)(T0 + 1) * 512 + ks * 64 + l];
    }

    // A fragments: 2 stripes x 8 ksteps, fp32 loads + in-reg cvt
    // (pair-partner wave reads the same rows: second read is L2 hit)
    bf16x8 af[2][8];
    #pragma unroll
    for (int s = 0; s < 2; ++s) {
        const float* rp = x + (size_t)(row0 + s * 16 + lr) * DIM + lh * 8;
        #pragma unroll
        for (int ks = 0; ks < 8; ++ks) {
            float4 a = *(const float4*)(rp + ks * 32);
            float4 bq = *(const float4*)(rp + ks * 32 + 4);
            bf16x8 o;
            o[0] = (short)f2bf(a.x);  o[1] = (short)f2bf(a.y);
            o[2] = (short)f2bf(a.z);  o[3] = (short)f2bf(a.w);
            o[4] = (short)f2bf(bq.x); o[5] = (short)f2bf(bq.y);
            o[6] = (short)f2bf(bq.z); o[7] = (short)f2bf(bq.w);
            af[s][ks] = o;
        }
    }

    unsigned best[2][4];
    #pragma unroll
    for (int s = 0; s < 2; ++s)
        #pragma unroll
        for (int r = 0; r < 4; ++r) best[s][r] = 0xFFFFFFFFu;

#define PHASE(TI, B, RT) do {                                                \
        const int ti_ = (TI);                                                \
        const int rt_ = (RT);                                                \
        float sv_ = seb[code0 + ti_ * 16 + lr];                              \
        f32x4 a0_ = (f32x4){0.f, 0.f, 0.f, 0.f};                             \
        f32x4 a1_ = (f32x4){0.f, 0.f, 0.f, 0.f};                             \
        _Pragma("unroll")                                                    \
        for (int ks = 0; ks < 8; ++ks) {                                     \
            a0_ = __builtin_amdgcn_mfma_f32_16x16x32_bf16(af[0][ks], B[ks], a0_, 0, 0, 0); \
            a1_ = __builtin_amdgcn_mfma_f32_16x16x32_bf16(af[1][ks], B[ks], a1_, 0, 0, 0); \
            if (rt_ >= 0) B[ks] = ebv[(size_t)rt_ * 512 + ks * 64 + l];      \
        }                                                                    \
        unsigned nl_ = (unsigned)(code0 + ti_ * 16) | (unsigned)lr;          \
        _Pragma("unroll")                                                    \
        for (int r = 0; r < 4; ++r) {                                        \
            float s0_ = fmaf(-2.0f, a0_[r], sv_);                            \
            best[0][r] = umin_(best[0][r],                                   \
                (__builtin_bit_cast(unsigned, s0_) & 0xFFFFFC00u) | nl_);    \
            float s1_ = fmaf(-2.0f, a1_[r], sv_);                            \
            best[1][r] = umin_(best[1][r],                                   \
                (__builtin_bit_cast(unsigned, s1_) & 0xFFFFFC00u) | nl_);    \
        }                                                                    \
    } while (0)

    #pragma unroll 1
    for (int ti = 0; ti < 30; ti += 2) {
        PHASE(ti,     bA, T0 + ti + 2);
        PHASE(ti + 1, bB, T0 + ti + 3);
    }
    PHASE(30, bA, -1);
    PHASE(31, bB, -1);
#undef PHASE

    // reduce over the 16 code-lanes (same lh): xor 1,2,4,8
    #pragma unroll
    for (int s = 0; s < 2; ++s)
        #pragma unroll
        for (int r = 0; r < 4; ++r) {
            unsigned v = best[s][r];
            #pragma unroll
            for (int m = 1; m <= 8; m <<= 1)
                v = umin_(v, (unsigned)__shfl_xor((int)v, m, 64));
            best[s][r] = v;
        }

    // ---- cross-half min-combine (wave pair shares the same 32 rows) ----
    __shared__ unsigned cmb[2][2][2][4][4];   // [rg][half][s][r][lh], 512 B
    if (lr == 0) {
        #pragma unroll
        for (int s = 0; s < 2; ++s)
            #pragma unroll
            for (int r = 0; r < 4; ++r)
                cmb[rg][half][s][r][lh] = best[s][r];
    }
    __syncthreads();
    #pragma unroll
    for (int s = 0; s < 2; ++s)
        #pragma unroll
        for (int r = 0; r < 4; ++r)
            best[s][r] = umin_(best[s][r], cmb[rg][half ^ 1][s][r][lh]);

    // eb-overlap blocks: rows [32768,33280) == out bytes [32MB,32.5MB)
    const bool skipout = (blockIdx.x >= 512 && blockIdx.x < 520);

    // duty split: wave `half` owns stripe s = half (16 rows)
    const int so = half;
    if (lr == 0) {
        #pragma unroll
        for (int r = 0; r < 4; ++r) {
            int code = (int)(best[so][r] & 1023u);
            atomicAdd(&counts[code], 1);
            if (skipout)
                fixidx[row0 + so * 16 + lh * 4 + r - 32768] = code;
        }
    }

    // fused K2 epilogue: 16 rows (own stripe), 2 groups of 8 (K2's exact math)
    float local = 0.f;
    #pragma unroll
    for (int g = 0; g < 2; ++g) {
        int code[8];
        #pragma unroll
        for (int j = 0; j < 8; ++j) {
            const int off = g * 8 + j;           // 0..15 within stripe
            const int h = off >> 2, r = off & 3; // row = so*16 + h*4 + r
            code[j] = (int)((unsigned)__shfl((int)best[so][r], h << 4, 64) & 1023u);
        }
        float4 xv[8];
        #pragma unroll
        for (int j = 0; j < 8; ++j)
            xv[j] = ((const float4*)x)[(size_t)(row0 + so * 16 + g * 8 + j) * 64 + l];
        float4 qv[8];
        #pragma unroll
        for (int j = 0; j < 8; ++j)
            qv[j] = ((const float4*)e)[(size_t)code[j] * 64 + l];
        #pragma unroll
        for (int j = 0; j < 8; ++j) {
            float4 d, o;
            d.x = qv[j].x - xv[j].x; d.y = qv[j].y - xv[j].y;
            d.z = qv[j].z - xv[j].z; d.w = qv[j].w - xv[j].w;
            o.x = xv[j].x + d.x;  o.y = xv[j].y + d.y;
            o.z = xv[j].z + d.z;  o.w = xv[j].w + d.w;
            if (!skipout)
                ((float4*)out)[(size_t)(row0 + so * 16 + g * 8 + j) * 64 + l] = o;
            local += d.x * d.x + d.y * d.y + d.z * d.z + d.w * d.w;
        }
    }
    #pragma unroll
    for (int m = 32; m >= 1; m >>= 1) local += __shfl_xor(local, m, 64);
    __shared__ float red[4];
    if (l == 0) red[wid] = local;
    __syncthreads();
    if (tid == 0) {
        float s = red[0] + red[1] + red[2] + red[3];
        atomicAdd(sumsq, (double)s);
    }
}

// ---------------------------------------------------------------------------
// K_fix: rewrite out rows [32768, 33280) (deferred because they alias eb).
// Runs after k_main (stream-ordered; eb dead).  Same arithmetic as epilogue.
// ---------------------------------------------------------------------------
__global__ __launch_bounds__(256)
void k_fix(const float* __restrict__ x, const float* __restrict__ e,
           const int* __restrict__ fixidx, float* __restrict__ out) {
    const int w = threadIdx.x >> 6;
    const int l = threadIdx.x & 63;
    const int rbase = blockIdx.x * 32 + w * 8;   // 0..511 local
    int k[8];
    #pragma unroll
    for (int r = 0; r < 8; ++r) k[r] = fixidx[rbase + r];
    float4 xv[8];
    #pragma unroll
    for (int r = 0; r < 8; ++r)
        xv[r] = ((const float4*)x)[(size_t)(32768 + rbase + r) * 64 + l];
    float4 qv[8];
    #pragma unroll
    for (int r = 0; r < 8; ++r)
        qv[r] = ((const float4*)e)[(size_t)k[r] * 64 + l];
    #pragma unroll
    for (int r = 0; r < 8; ++r) {
        float4 d, o;
        d.x = qv[r].x - xv[r].x; d.y = qv[r].y - xv[r].y;
        d.z = qv[r].z - xv[r].z; d.w = qv[r].w - xv[r].w;
        o.x = xv[r].x + d.x;  o.y = xv[r].y + d.y;
        o.z = xv[r].z + d.z;  o.w = xv[r].w + d.w;
        ((float4*)out)[(size_t)(32768 + rbase + r) * 64 + l] = o;
    }
}

// ---------------------------------------------------------------------------
// K4: finalize loss + perplexity (single block)
// ---------------------------------------------------------------------------
__global__ __launch_bounds__(256)
void k_fin(const int* __restrict__ counts, const double* __restrict__ sumsq,
           float* __restrict__ out_scalars) {
    float local = 0.f;
    for (int c = threadIdx.x; c < NCODE; c += 256) {
        float p = (float)counts[c] * (1.0f / 65536.0f);
        local += p * logf(p + 1e-10f);
    }
    #pragma unroll
    for (int m = 32; m >= 1; m >>= 1) local += __shfl_xor(local, m, 64);
    __shared__ float red[4];
    if ((threadIdx.x & 63) == 0) red[threadIdx.x >> 6] = local;
    __syncthreads();
    if (threadIdx.x == 0) {
        float s = red[0] + red[1] + red[2] + red[3];
        float perp = expf(-s);
        float m = (float)(*sumsq * (1.0 / 16777216.0));
        float loss = m + 0.25f * m;
        out_scalars[0] = loss;
        out_scalars[1] = perp;
    }
}

// ---------------------------------------------------------------------------
extern "C" void kernel_launch(void* const* d_in, const int* in_sizes, int n_in,
                              void* d_out, int out_size, void* d_ws, size_t ws_size,
                              hipStream_t stream) {
    const float* x   = (const float*)d_in[0];   // [65536, 256]
    const float* emb = (const float*)d_in[1];   // [1024, 256]
    float* out = (float*)d_out;                 // [16777216 + 2]

    // small workspace (~11 KB)
    float*    seb    = (float*)d_ws;                        // 4 KB
    int*      counts = (int*)((char*)d_ws + 4096);          // 4 KB
    double*   sumsq  = (double*)((char*)d_ws + 8192);       // 8 B
    int*      fixidx = (int*)((char*)d_ws + 8704);          // 2 KB (512 rows)

    // eb scratch lives in d_out at +32MB: read by k_main, whose out-writes
    // SKIP that byte range (blocks 512..519); k_fix patches it afterwards.
    unsigned short* eb = (unsigned short*)((char*)d_out + 33554432); // 512 KB

    k_prep <<<133,        256, 0, stream>>>(emb, seb, eb, counts, sumsq);
    k_main <<<NROWS / 64, 256, 0, stream>>>(x, emb, eb, seb, out, counts, sumsq, fixidx);
    k_fix  <<<16,         256, 0, stream>>>(x, emb, fixidx, out);
    k_fin  <<<1,          256, 0, stream>>>(counts, sumsq, out + OUT_ELEMS);
}